// Round 1
// baseline (469.487 us; speedup 1.0000x reference)
//
#include <hip/hip_runtime.h>
#include <hip/hip_bf16.h>

// FourierKANLayer: N=4096, D_IN=512, D_OUT=512, G=32
// y = [cos/sin(k*LN(x)) features] @ W + bias  == GEMM M=4096,N=512,K=32768 (bf16 MFMA)
// ws layout: [0,8MB) xn^T fp32 [512][4096]; [8MB,41.5MB) bf16 weights [2][512][16384]

#define N_ROWS 4096
#define D_IN   512
#define D_OUT  512
#define KT     16384   // per-trig K = D_IN*G
#define BM 128
#define BN 128
#define BK 64
#define LDA 72         // padded LDS leading dim (bf16 units); 144B rows keep 16B align

typedef short short8 __attribute__((ext_vector_type(8)));
typedef float float4v __attribute__((ext_vector_type(4)));

__device__ inline unsigned int pack2bf(float a, float b) {
    __hip_bfloat162 h = __float22bfloat162_rn(make_float2(a, b));
    union { __hip_bfloat162 h; unsigned int u; } cv;
    cv.h = h;
    return cv.u;
}

// ---- kernel 1: LayerNorm, writes xn transposed (xnT[i][b]) ----
__global__ __launch_bounds__(256) void ln_kernel(const float* __restrict__ x,
        const float* __restrict__ w, const float* __restrict__ b,
        float* __restrict__ xnT) {
    const int row = blockIdx.x;
    const int t = threadIdx.x;
    float v0 = x[(size_t)row * D_IN + t];
    float v1 = x[(size_t)row * D_IN + t + 256];
    float s = v0 + v1;
    float q = v0 * v0 + v1 * v1;
    #pragma unroll
    for (int off = 32; off > 0; off >>= 1) {
        s += __shfl_down(s, off, 64);
        q += __shfl_down(q, off, 64);
    }
    __shared__ float red[8];
    __shared__ float mu_s, rs_s;
    const int lane = t & 63, wv = t >> 6;
    if (lane == 0) { red[wv] = s; red[wv + 4] = q; }
    __syncthreads();
    if (t == 0) {
        float S = red[0] + red[1] + red[2] + red[3];
        float Q = red[4] + red[5] + red[6] + red[7];
        float mu = S * (1.f / D_IN);
        float var = Q * (1.f / D_IN) - mu * mu;
        mu_s = mu;
        rs_s = rsqrtf(var + 1e-5f);
    }
    __syncthreads();
    const float mu = mu_s, rs = rs_s;
    xnT[(size_t)t * N_ROWS + row]         = (v0 - mu) * rs * w[t] + b[t];
    xnT[(size_t)(t + 256) * N_ROWS + row] = (v1 - mu) * rs * w[t + 256] + b[t + 256];
}

// ---- kernel 2: cast fouriercoeffs fp32 -> bf16 (layout preserved: [t][o][i*32+g]) ----
__global__ __launch_bounds__(256) void cvt_kernel(const float* __restrict__ fc,
        unsigned short* __restrict__ Wb) {
    size_t e = ((size_t)blockIdx.x * 256 + threadIdx.x) * 8;
    const float4* in = (const float4*)(fc + e);
    float4 a = in[0];
    float4 c = in[1];
    uint4 o;
    o.x = pack2bf(a.x, a.y);
    o.y = pack2bf(a.z, a.w);
    o.z = pack2bf(c.x, c.y);
    o.w = pack2bf(c.z, c.w);
    *(uint4*)(Wb + e) = o;
}

// ---- kernel 3: out = broadcast(bias) (split-K accumulates on top) ----
__global__ __launch_bounds__(256) void init_kernel(const float* __restrict__ bias,
        float* __restrict__ out) {
    size_t e = ((size_t)blockIdx.x * 256 + threadIdx.x) * 4;
    const float4 bv = *(const float4*)(bias + (e & (D_OUT - 1)));
    *(float4*)(out + e) = bv;
}

// ---- kernel 4: fused feature-gen + bf16 MFMA GEMM, split-K=8, atomicAdd epilogue ----
// grid (32 row-tiles, 4 col-tiles, 8 k-chunks); chunk>>2 = trig (0 cos / 1 sin)
__global__ __launch_bounds__(256) void fkan_gemm(const float* __restrict__ xnT,
        const unsigned short* __restrict__ Wb, float* __restrict__ out) {
    __shared__ unsigned short As[BM * LDA];
    __shared__ unsigned short Bs[BN * LDA];
    const int t = threadIdx.x;
    const int row0 = blockIdx.x * BM;
    const int col0 = blockIdx.y * BN;
    const int chunk = blockIdx.z;
    const int ttype = chunk >> 2;
    const int k0 = (chunk & 3) * 4096;   // within-trig k offset
    const int i0 = k0 >> 5;              // starting input dim for this chunk
    // feature staging: thread -> (row, which-of-2-input-dims)
    const int frow = t & 127;
    const int ihalf = t >> 7;
    // B staging: thread -> (col line, 8-element k segment)
    const int bc = t >> 3;
    const int bk8 = (t & 7) * 8;
    const unsigned short* Wt = Wb + (size_t)ttype * D_OUT * KT + k0 + bk8;
    // wave/lane ids for MFMA
    const int l = t & 63, wv = t >> 6;
    const int wm = (wv & 1) * 64, wn = (wv >> 1) * 64;
    const int lm = l & 15, lq = l >> 4;

    float4v acc[4][4];
    #pragma unroll
    for (int i = 0; i < 4; ++i)
        #pragma unroll
        for (int j = 0; j < 4; ++j)
            acc[i][j] = (float4v){0.f, 0.f, 0.f, 0.f};

    // prefetch iter 0
    float theta = xnT[(size_t)(i0 + ihalf) * N_ROWS + row0 + frow];
    uint4 bv[4];
    #pragma unroll
    for (int r = 0; r < 4; ++r)
        bv[r] = *(const uint4*)(Wt + (size_t)(col0 + bc + r * 32) * KT);

    for (int iter = 0; iter < 64; ++iter) {
        // ---- features for (frow, i = i0 + 2*iter + ihalf): trig((g+1)*theta), g=0..31
        // Chebyshev: T_{n+1} = 2cos(theta)*T_n - T_{n-1} for both cos and sin chains
        float s1, c1;
        __sincosf(theta, &s1, &c1);
        const float c2 = 2.f * c1;
        float prev = ttype ? 0.f : 1.f;
        float cur  = ttype ? s1 : c1;
        unsigned int u[16];
        #pragma unroll
        for (int d = 0; d < 16; ++d) {
            float f0 = cur;
            float f1 = c2 * cur - prev;
            float f2 = c2 * f1 - cur;
            prev = f1;
            cur = f2;
            u[d] = pack2bf(f0, f1);
        }
        __syncthreads();   // previous iter's MFMA reads done
        {
            uint4* dst = (uint4*)&As[frow * LDA + ihalf * 32];
            dst[0] = make_uint4(u[0], u[1], u[2], u[3]);
            dst[1] = make_uint4(u[4], u[5], u[6], u[7]);
            dst[2] = make_uint4(u[8], u[9], u[10], u[11]);
            dst[3] = make_uint4(u[12], u[13], u[14], u[15]);
            #pragma unroll
            for (int r = 0; r < 4; ++r)
                *(uint4*)&Bs[(bc + r * 32) * LDA + bk8] = bv[r];
        }
        // prefetch next iter (lands during MFMA phase)
        if (iter < 63) {
            theta = xnT[(size_t)(i0 + (iter + 1) * 2 + ihalf) * N_ROWS + row0 + frow];
            const unsigned short* wsrc = Wt + (iter + 1) * 64;
            #pragma unroll
            for (int r = 0; r < 4; ++r)
                bv[r] = *(const uint4*)(wsrc + (size_t)(col0 + bc + r * 32) * KT);
        }
        __syncthreads();   // tiles visible
        #pragma unroll
        for (int kk = 0; kk < BK; kk += 32) {
            short8 af[4], bfr[4];
            #pragma unroll
            for (int tm = 0; tm < 4; ++tm)
                af[tm] = *(const short8*)&As[(wm + tm * 16 + lm) * LDA + kk + lq * 8];
            #pragma unroll
            for (int tn = 0; tn < 4; ++tn)
                bfr[tn] = *(const short8*)&Bs[(wn + tn * 16 + lm) * LDA + kk + lq * 8];
            #pragma unroll
            for (int tm = 0; tm < 4; ++tm)
                #pragma unroll
                for (int tn = 0; tn < 4; ++tn)
                    acc[tm][tn] = __builtin_amdgcn_mfma_f32_16x16x32_bf16(
                        af[tm], bfr[tn], acc[tm][tn], 0, 0, 0);
        }
    }
    // epilogue: C/D layout col=lane&15, row=quad*4+reg (m89-verified)
    #pragma unroll
    for (int tm = 0; tm < 4; ++tm)
        #pragma unroll
        for (int tn = 0; tn < 4; ++tn)
            #pragma unroll
            for (int r = 0; r < 4; ++r) {
                int row = row0 + wm + tm * 16 + lq * 4 + r;
                int col = col0 + wn + tn * 16 + lm;
                atomicAdd(&out[(size_t)row * D_OUT + col], acc[tm][tn][r]);
            }
}

extern "C" void kernel_launch(void* const* d_in, const int* in_sizes, int n_in,
                              void* d_out, int out_size, void* d_ws, size_t ws_size,
                              hipStream_t stream) {
    const float* x    = (const float*)d_in[0];
    const float* ln_w = (const float*)d_in[1];
    const float* ln_b = (const float*)d_in[2];
    const float* fc   = (const float*)d_in[3];
    const float* bias = (const float*)d_in[4];
    float* out = (float*)d_out;

    float* xnT = (float*)d_ws;                                        // 8 MB
    unsigned short* Wb = (unsigned short*)((char*)d_ws + (8u << 20)); // 33.5 MB

    ln_kernel<<<N_ROWS, 256, 0, stream>>>(x, ln_w, ln_b, xnT);
    cvt_kernel<<<8192, 256, 0, stream>>>(fc, Wb);                     // 16.78M elems
    init_kernel<<<2048, 256, 0, stream>>>(bias, out);                 // 2.10M elems
    fkan_gemm<<<dim3(N_ROWS / BM, D_OUT / BN, 8), 256, 0, stream>>>(xnT, Wb, out);
}

// Round 2
// 430.940 us; speedup vs baseline: 1.0895x; 1.0895x over previous
//
#include <hip/hip_runtime.h>
#include <hip/hip_bf16.h>

// FourierKANLayer: N=4096, D_IN=512, D_OUT=512, G=32
// y = [cos/sin(k*LN(x)) features] @ W + bias  == GEMM M=4096,N=512,K=32768 (bf16 MFMA)
// ws layout: [0,16MB) csT float2[512][4096] = (cos xn, sin xn) transposed seeds
//            [16MB,+32KB) mu_rs float2[4096]
//            [17MB,+33.5MB) bf16 weights [2][512][16384]

#define N_ROWS 4096
#define D_IN   512
#define D_OUT  512
#define KT     16384   // per-trig K = D_IN*G
#define BM 128
#define BN 128
#define BK 64
#define LDA 72         // padded LDS leading dim (bf16 units); 144B rows keep 16B align

typedef short short8 __attribute__((ext_vector_type(8)));
typedef float float4v __attribute__((ext_vector_type(4)));

__device__ inline unsigned int pack2bf(float a, float b) {
    __hip_bfloat162 h = __float22bfloat162_rn(make_float2(a, b));
    union { __hip_bfloat162 h; unsigned int u; } cv;
    cv.h = h;
    return cv.u;
}

// ---- kernel 1: per-row LayerNorm stats (mu, rsqrt(var+eps)) ----
__global__ __launch_bounds__(256) void ln_stats(const float* __restrict__ x,
        float2* __restrict__ mu_rs) {
    const int t = threadIdx.x;
    const int row = blockIdx.x * 4 + (t >> 6);
    const int lane = t & 63;
    const float4* xr = (const float4*)(x + (size_t)row * D_IN);
    float4 a = xr[lane];
    float4 c = xr[lane + 64];
    float s = a.x + a.y + a.z + a.w + c.x + c.y + c.z + c.w;
    float q = a.x * a.x + a.y * a.y + a.z * a.z + a.w * a.w
            + c.x * c.x + c.y * c.y + c.z * c.z + c.w * c.w;
    #pragma unroll
    for (int off = 32; off > 0; off >>= 1) {
        s += __shfl_down(s, off, 64);
        q += __shfl_down(q, off, 64);
    }
    if (lane == 0) {
        float mu = s * (1.f / D_IN);
        float var = q * (1.f / D_IN) - mu * mu;
        mu_rs[row] = make_float2(mu, rsqrtf(var + 1e-5f));
    }
}

// ---- kernel 2: normalize + sincos seeds, transposed coalesced write ----
// csT[i][row] = (cos(xn), sin(xn)); tile 64 rows x 64 dims through LDS
__global__ __launch_bounds__(256) void feat_seed(const float* __restrict__ x,
        const float* __restrict__ w, const float* __restrict__ b,
        const float2* __restrict__ mu_rs, float2* __restrict__ csT) {
    __shared__ float2 tile[64][66];
    const int t = threadIdx.x;
    const int r0 = blockIdx.x * 64, i0 = blockIdx.y * 64;
    const int rr = t >> 6;      // 0..3
    const int cc = t & 63;
    const float wv = w[i0 + cc], bv = b[i0 + cc];
    #pragma unroll
    for (int p = 0; p < 16; ++p) {
        const int row = r0 + p * 4 + rr;
        float v = x[(size_t)row * D_IN + i0 + cc];
        float2 mr = mu_rs[row];
        float xn = (v - mr.x) * mr.y * wv + bv;
        float sn, cn;
        __sincosf(xn, &sn, &cn);
        tile[cc][p * 4 + rr] = make_float2(cn, sn);
    }
    __syncthreads();
    #pragma unroll
    for (int p = 0; p < 16; ++p) {
        const int dim = p * 4 + rr;
        csT[(size_t)(i0 + dim) * N_ROWS + r0 + cc] = tile[dim][cc];
    }
}

// ---- kernel 3: cast fouriercoeffs fp32 -> bf16 (layout preserved: [t][o][i*32+g]) ----
__global__ __launch_bounds__(256) void cvt_kernel(const float* __restrict__ fc,
        unsigned short* __restrict__ Wb) {
    size_t e = ((size_t)blockIdx.x * 256 + threadIdx.x) * 8;
    const float4* in = (const float4*)(fc + e);
    float4 a = in[0];
    float4 c = in[1];
    uint4 o;
    o.x = pack2bf(a.x, a.y);
    o.y = pack2bf(a.z, a.w);
    o.z = pack2bf(c.x, c.y);
    o.w = pack2bf(c.z, c.w);
    *(uint4*)(Wb + e) = o;
}

// ---- kernel 4: out = broadcast(bias) (split-K accumulates on top) ----
__global__ __launch_bounds__(256) void init_kernel(const float* __restrict__ bias,
        float* __restrict__ out) {
    size_t e = ((size_t)blockIdx.x * 256 + threadIdx.x) * 4;
    const float4 bv = *(const float4*)(bias + (e & (D_OUT - 1)));
    *(float4*)(out + e) = bv;
}

// ---- kernel 5: fused feature-gen + bf16 MFMA GEMM, split-K=8, atomicAdd epilogue ----
// grid (32 row-tiles, 4 col-tiles, 8 k-chunks); chunk>>2 = trig (0 cos / 1 sin)
// __launch_bounds__(256,4): cap 128 regs/wave -> 4 blocks/CU (LDS 4*36864 fits 160K)
__global__ __launch_bounds__(256, 4) void fkan_gemm(const float2* __restrict__ csT,
        const unsigned short* __restrict__ Wb, float* __restrict__ out) {
    __shared__ unsigned short As[BM * LDA];
    __shared__ unsigned short Bs[BN * LDA];
    const int t = threadIdx.x;
    const int row0 = blockIdx.x * BM;
    const int col0 = blockIdx.y * BN;
    const int chunk = blockIdx.z;
    const int ttype = chunk >> 2;
    const int k0 = (chunk & 3) * 4096;   // within-trig k offset
    const int i0 = k0 >> 5;              // starting input dim for this chunk
    // feature staging: thread -> (row, which-of-2-input-dims)
    const int frow = t & 127;
    const int ihalf = t >> 7;
    // B staging: thread -> (col line, 8-element k segment)
    const int bc = t >> 3;
    const int bk8 = (t & 7) * 8;
    const unsigned short* Wt = Wb + (size_t)ttype * D_OUT * KT + k0 + bk8;
    // wave/lane ids for MFMA
    const int l = t & 63, wv = t >> 6;
    const int wm = (wv & 1) * 64, wn = (wv >> 1) * 64;
    const int lm = l & 15, lq = l >> 4;

    float4v acc[4][4];
    #pragma unroll
    for (int i = 0; i < 4; ++i)
        #pragma unroll
        for (int j = 0; j < 4; ++j)
            acc[i][j] = (float4v){0.f, 0.f, 0.f, 0.f};

    // prefetch iter 0 (seeds + B tile in registers; live across barrier 1)
    float2 cs = csT[(size_t)(i0 + ihalf) * N_ROWS + row0 + frow];
    uint4 bv[4];
    #pragma unroll
    for (int r = 0; r < 4; ++r)
        bv[r] = *(const uint4*)(Wt + (size_t)(col0 + bc + r * 32) * KT);

    for (int iter = 0; iter < 64; ++iter) {
        __syncthreads();   // previous iter's MFMA reads done -> safe to overwrite
        // ---- stage B from register prefetch
        #pragma unroll
        for (int r = 0; r < 4; ++r)
            *(uint4*)&Bs[(bc + r * 32) * LDA + bk8] = bv[r];
        // ---- stage A: Chebyshev chains from precomputed (cos t, sin t),
        //      write 16B chunks as they are produced (low register pressure)
        {
            const float c1 = cs.x, s1 = cs.y;
            const float c2 = 2.f * c1;
            float prev = ttype ? 0.f : 1.f;
            float cur  = ttype ? s1 : c1;
            uint4* dst = (uint4*)&As[frow * LDA + ihalf * 32];
            unsigned int us[4];
            #pragma unroll
            for (int d = 0; d < 16; ++d) {
                float f0 = cur;
                float f1 = c2 * cur - prev;
                float f2 = c2 * f1 - cur;
                prev = f1;
                cur = f2;
                us[d & 3] = pack2bf(f0, f1);
                if ((d & 3) == 3)
                    dst[d >> 2] = make_uint4(us[0], us[1], us[2], us[3]);
            }
        }
        // prefetch next iter (lands during MFMA phase)
        if (iter < 63) {
            cs = csT[(size_t)(i0 + (iter + 1) * 2 + ihalf) * N_ROWS + row0 + frow];
            const unsigned short* wsrc = Wt + (iter + 1) * 64;
            #pragma unroll
            for (int r = 0; r < 4; ++r)
                bv[r] = *(const uint4*)(wsrc + (size_t)(col0 + bc + r * 32) * KT);
        }
        __syncthreads();   // tiles visible
        #pragma unroll
        for (int kk = 0; kk < BK; kk += 32) {
            short8 af[4], bfr[4];
            #pragma unroll
            for (int tm = 0; tm < 4; ++tm)
                af[tm] = *(const short8*)&As[(wm + tm * 16 + lm) * LDA + kk + lq * 8];
            #pragma unroll
            for (int tn = 0; tn < 4; ++tn)
                bfr[tn] = *(const short8*)&Bs[(wn + tn * 16 + lm) * LDA + kk + lq * 8];
            #pragma unroll
            for (int tm = 0; tm < 4; ++tm)
                #pragma unroll
                for (int tn = 0; tn < 4; ++tn)
                    acc[tm][tn] = __builtin_amdgcn_mfma_f32_16x16x32_bf16(
                        af[tm], bfr[tn], acc[tm][tn], 0, 0, 0);
        }
    }
    // epilogue: C/D layout col=lane&15, row=quad*4+reg (m89-verified)
    #pragma unroll
    for (int tm = 0; tm < 4; ++tm)
        #pragma unroll
        for (int tn = 0; tn < 4; ++tn)
            #pragma unroll
            for (int r = 0; r < 4; ++r) {
                int row = row0 + wm + tm * 16 + lq * 4 + r;
                int col = col0 + wn + tn * 16 + lm;
                atomicAdd(&out[(size_t)row * D_OUT + col], acc[tm][tn][r]);
            }
}

extern "C" void kernel_launch(void* const* d_in, const int* in_sizes, int n_in,
                              void* d_out, int out_size, void* d_ws, size_t ws_size,
                              hipStream_t stream) {
    const float* x    = (const float*)d_in[0];
    const float* ln_w = (const float*)d_in[1];
    const float* ln_b = (const float*)d_in[2];
    const float* fc   = (const float*)d_in[3];
    const float* bias = (const float*)d_in[4];
    float* out = (float*)d_out;

    float2* csT = (float2*)d_ws;                                       // 16 MB
    float2* mu_rs = (float2*)((char*)d_ws + (16u << 20));              // 32 KB
    unsigned short* Wb = (unsigned short*)((char*)d_ws + (17u << 20)); // 33.5 MB

    ln_stats<<<N_ROWS / 4, 256, 0, stream>>>(x, mu_rs);
    feat_seed<<<dim3(N_ROWS / 64, D_IN / 64), 256, 0, stream>>>(x, ln_w, ln_b, mu_rs, csT);
    cvt_kernel<<<8192, 256, 0, stream>>>(fc, Wb);                      // 16.78M elems
    init_kernel<<<2048, 256, 0, stream>>>(bias, out);                  // 2.10M elems
    fkan_gemm<<<dim3(N_ROWS / BM, D_OUT / BN, 8), 256, 0, stream>>>(csT, Wb, out);
}

// Round 3
// 419.005 us; speedup vs baseline: 1.1205x; 1.0285x over previous
//
#include <hip/hip_runtime.h>
#include <hip/hip_bf16.h>

// FourierKANLayer: N=4096, D_IN=512, D_OUT=512, G=32
// y = [cos/sin(k*LN(x)) features] @ W + bias  == GEMM M=4096,N=512,K=32768 (bf16 MFMA)
// ws layout: [0,16MB)  csT float2[512][4096] = (cos xn, sin xn) transposed seeds
//            [16MB]    mu_rs float2[4096] (32 KB)
//            [17MB]    bf16 weights [2][512][16384] (33.5 MB)
//            [51MB]    bf16 split-K partials [8][4096][512] (33.5 MB)

#define N_ROWS 4096
#define D_IN   512
#define D_OUT  512
#define KT     16384   // per-trig K = D_IN*G
#define BM 128
#define BN 128
#define BK 64
#define LDA 72         // padded LDS leading dim (bf16 units); 144B rows keep 16B align

typedef short short8 __attribute__((ext_vector_type(8)));
typedef float float4v __attribute__((ext_vector_type(4)));

__device__ inline unsigned int pack2bf(float a, float b) {
    __hip_bfloat162 h = __float22bfloat162_rn(make_float2(a, b));
    union { __hip_bfloat162 h; unsigned int u; } cv;
    cv.h = h;
    return cv.u;
}

__device__ inline unsigned short bf16_1(float a) {
    union { float f; unsigned int u; } cv;
    cv.f = a;
    unsigned int r = (cv.u + 0x7fff + ((cv.u >> 16) & 1)) >> 16;  // RN-even
    return (unsigned short)r;
}

// ---- kernel 1: per-row LayerNorm stats (mu, rsqrt(var+eps)) ----
__global__ __launch_bounds__(256) void ln_stats(const float* __restrict__ x,
        float2* __restrict__ mu_rs) {
    const int t = threadIdx.x;
    const int row = blockIdx.x * 4 + (t >> 6);
    const int lane = t & 63;
    const float4* xr = (const float4*)(x + (size_t)row * D_IN);
    float4 a = xr[lane];
    float4 c = xr[lane + 64];
    float s = a.x + a.y + a.z + a.w + c.x + c.y + c.z + c.w;
    float q = a.x * a.x + a.y * a.y + a.z * a.z + a.w * a.w
            + c.x * c.x + c.y * c.y + c.z * c.z + c.w * c.w;
    #pragma unroll
    for (int off = 32; off > 0; off >>= 1) {
        s += __shfl_down(s, off, 64);
        q += __shfl_down(q, off, 64);
    }
    if (lane == 0) {
        float mu = s * (1.f / D_IN);
        float var = q * (1.f / D_IN) - mu * mu;
        mu_rs[row] = make_float2(mu, rsqrtf(var + 1e-5f));
    }
}

// ---- kernel 2: normalize + sincos seeds, transposed coalesced write ----
// csT[i][row] = (cos(xn), sin(xn)); tile 64 rows x 64 dims through LDS
__global__ __launch_bounds__(256) void feat_seed(const float* __restrict__ x,
        const float* __restrict__ w, const float* __restrict__ b,
        const float2* __restrict__ mu_rs, float2* __restrict__ csT) {
    __shared__ float2 tile[64][66];
    const int t = threadIdx.x;
    const int r0 = blockIdx.x * 64, i0 = blockIdx.y * 64;
    const int rr = t >> 6;      // 0..3
    const int cc = t & 63;
    const float wv = w[i0 + cc], bv = b[i0 + cc];
    #pragma unroll
    for (int p = 0; p < 16; ++p) {
        const int row = r0 + p * 4 + rr;
        float v = x[(size_t)row * D_IN + i0 + cc];
        float2 mr = mu_rs[row];
        float xn = (v - mr.x) * mr.y * wv + bv;
        float sn, cn;
        __sincosf(xn, &sn, &cn);
        tile[cc][p * 4 + rr] = make_float2(cn, sn);
    }
    __syncthreads();
    #pragma unroll
    for (int p = 0; p < 16; ++p) {
        const int dim = p * 4 + rr;
        csT[(size_t)(i0 + dim) * N_ROWS + r0 + cc] = tile[dim][cc];
    }
}

// ---- kernel 3: cast fouriercoeffs fp32 -> bf16 (layout preserved: [t][o][i*32+g]) ----
__global__ __launch_bounds__(256) void cvt_kernel(const float* __restrict__ fc,
        unsigned short* __restrict__ Wb) {
    size_t e = ((size_t)blockIdx.x * 256 + threadIdx.x) * 8;
    const float4* in = (const float4*)(fc + e);
    float4 a = in[0];
    float4 c = in[1];
    uint4 o;
    o.x = pack2bf(a.x, a.y);
    o.y = pack2bf(a.z, a.w);
    o.z = pack2bf(c.x, c.y);
    o.w = pack2bf(c.z, c.w);
    *(uint4*)(Wb + e) = o;
}

// ---- kernel 4: fused feature-gen + bf16 MFMA GEMM, split-K=8 ----
// grid (32 row-tiles, 4 col-tiles, 8 k-chunks); chunk>>2 = trig (0 cos / 1 sin)
// NON-ATOMIC epilogue: bf16 partial tile -> pb[chunk] (reduced by kernel 5)
__global__ __launch_bounds__(256, 4) void fkan_gemm(const float2* __restrict__ csT,
        const unsigned short* __restrict__ Wb, unsigned short* __restrict__ pb) {
    __shared__ unsigned short As[BM * LDA];
    __shared__ unsigned short Bs[BN * LDA];
    const int t = threadIdx.x;
    const int row0 = blockIdx.x * BM;
    const int col0 = blockIdx.y * BN;
    const int chunk = blockIdx.z;
    const int ttype = chunk >> 2;
    const int k0 = (chunk & 3) * 4096;   // within-trig k offset
    const int i0 = k0 >> 5;              // starting input dim for this chunk
    // feature staging: thread -> (row, which-of-2-input-dims)
    const int frow = t & 127;
    const int ihalf = t >> 7;
    // B staging: thread -> (col line, 8-element k segment)
    const int bc = t >> 3;
    const int bk8 = (t & 7) * 8;
    const unsigned short* Wt = Wb + (size_t)ttype * D_OUT * KT + k0 + bk8;
    // wave/lane ids for MFMA
    const int l = t & 63, wv = t >> 6;
    const int wm = (wv & 1) * 64, wn = (wv >> 1) * 64;
    const int lm = l & 15, lq = l >> 4;

    float4v acc[4][4];
    #pragma unroll
    for (int i = 0; i < 4; ++i)
        #pragma unroll
        for (int j = 0; j < 4; ++j)
            acc[i][j] = (float4v){0.f, 0.f, 0.f, 0.f};

    // prefetch iter 0 (seeds + B tile in registers; live across barrier 1)
    float2 cs = csT[(size_t)(i0 + ihalf) * N_ROWS + row0 + frow];
    uint4 bv[4];
    #pragma unroll
    for (int r = 0; r < 4; ++r)
        bv[r] = *(const uint4*)(Wt + (size_t)(col0 + bc + r * 32) * KT);

    for (int iter = 0; iter < 64; ++iter) {
        __syncthreads();   // previous iter's MFMA reads done -> safe to overwrite
        // ---- stage B from register prefetch
        #pragma unroll
        for (int r = 0; r < 4; ++r)
            *(uint4*)&Bs[(bc + r * 32) * LDA + bk8] = bv[r];
        // ---- stage A: Chebyshev chains from precomputed (cos t, sin t)
        {
            const float c1 = cs.x, s1 = cs.y;
            const float c2 = 2.f * c1;
            float prev = ttype ? 0.f : 1.f;
            float cur  = ttype ? s1 : c1;
            uint4* dst = (uint4*)&As[frow * LDA + ihalf * 32];
            unsigned int us[4];
            #pragma unroll
            for (int d = 0; d < 16; ++d) {
                float f0 = cur;
                float f1 = c2 * cur - prev;
                float f2 = c2 * f1 - cur;
                prev = f1;
                cur = f2;
                us[d & 3] = pack2bf(f0, f1);
                if ((d & 3) == 3)
                    dst[d >> 2] = make_uint4(us[0], us[1], us[2], us[3]);
            }
        }
        // prefetch next iter (lands during MFMA phase)
        if (iter < 63) {
            cs = csT[(size_t)(i0 + (iter + 1) * 2 + ihalf) * N_ROWS + row0 + frow];
            const unsigned short* wsrc = Wt + (iter + 1) * 64;
            #pragma unroll
            for (int r = 0; r < 4; ++r)
                bv[r] = *(const uint4*)(wsrc + (size_t)(col0 + bc + r * 32) * KT);
        }
        __syncthreads();   // tiles visible
        #pragma unroll
        for (int kk = 0; kk < BK; kk += 32) {
            short8 af[4], bfr[4];
            #pragma unroll
            for (int tm = 0; tm < 4; ++tm)
                af[tm] = *(const short8*)&As[(wm + tm * 16 + lm) * LDA + kk + lq * 8];
            #pragma unroll
            for (int tn = 0; tn < 4; ++tn)
                bfr[tn] = *(const short8*)&Bs[(wn + tn * 16 + lm) * LDA + kk + lq * 8];
            #pragma unroll
            for (int tm = 0; tm < 4; ++tm)
                #pragma unroll
                for (int tn = 0; tn < 4; ++tn)
                    acc[tm][tn] = __builtin_amdgcn_mfma_f32_16x16x32_bf16(
                        af[tm], bfr[tn], acc[tm][tn], 0, 0, 0);
        }
    }
    // epilogue: C/D layout col=lane&15, row=quad*4+reg (m89-verified)
    // non-atomic bf16 partial store; reduce kernel sums the 8 chunks
    unsigned short* pc = pb + (size_t)chunk * N_ROWS * D_OUT;
    #pragma unroll
    for (int tm = 0; tm < 4; ++tm)
        #pragma unroll
        for (int tn = 0; tn < 4; ++tn)
            #pragma unroll
            for (int r = 0; r < 4; ++r) {
                int row = row0 + wm + tm * 16 + lq * 4 + r;
                int col = col0 + wn + tn * 16 + lm;
                pc[(size_t)row * D_OUT + col] = bf16_1(acc[tm][tn][r]);
            }
}

// ---- kernel 5: out = bias + sum of 8 bf16 partials (coalesced) ----
__global__ __launch_bounds__(256) void reduce_kernel(const unsigned short* __restrict__ pb,
        const float* __restrict__ bias, float* __restrict__ out) {
    const size_t e = ((size_t)blockIdx.x * 256 + threadIdx.x) * 4;
    const int col = (int)(e & (D_OUT - 1));
    float4 s = *(const float4*)(bias + col);
    #pragma unroll
    for (int c = 0; c < 8; ++c) {
        ushort4 u = *(const ushort4*)(pb + (size_t)c * N_ROWS * D_OUT + e);
        union { unsigned int u; float f; } f0, f1, f2, f3;
        f0.u = (unsigned int)u.x << 16;
        f1.u = (unsigned int)u.y << 16;
        f2.u = (unsigned int)u.z << 16;
        f3.u = (unsigned int)u.w << 16;
        s.x += f0.f; s.y += f1.f; s.z += f2.f; s.w += f3.f;
    }
    *(float4*)(out + e) = s;
}

extern "C" void kernel_launch(void* const* d_in, const int* in_sizes, int n_in,
                              void* d_out, int out_size, void* d_ws, size_t ws_size,
                              hipStream_t stream) {
    const float* x    = (const float*)d_in[0];
    const float* ln_w = (const float*)d_in[1];
    const float* ln_b = (const float*)d_in[2];
    const float* fc   = (const float*)d_in[3];
    const float* bias = (const float*)d_in[4];
    float* out = (float*)d_out;

    float2* csT = (float2*)d_ws;                                       // 16 MB
    float2* mu_rs = (float2*)((char*)d_ws + (16u << 20));              // 32 KB
    unsigned short* Wb = (unsigned short*)((char*)d_ws + (17u << 20)); // 33.5 MB
    unsigned short* pbp = (unsigned short*)((char*)d_ws + (51u << 20)); // 33.5 MB

    ln_stats<<<N_ROWS / 4, 256, 0, stream>>>(x, mu_rs);
    feat_seed<<<dim3(N_ROWS / 64, D_IN / 64), 256, 0, stream>>>(x, ln_w, ln_b, mu_rs, csT);
    cvt_kernel<<<8192, 256, 0, stream>>>(fc, Wb);                      // 16.78M elems
    fkan_gemm<<<dim3(N_ROWS / BM, D_OUT / BN, 8), 256, 0, stream>>>(csT, Wb, pbp);
    reduce_kernel<<<2048, 256, 0, stream>>>(pbp, bias, out);           // 2.10M outs
}

// Round 4
// 363.504 us; speedup vs baseline: 1.2916x; 1.1527x over previous
//
#include <hip/hip_runtime.h>
#include <hip/hip_bf16.h>

// FourierKANLayer: N=4096, D_IN=512, D_OUT=512, G=32
// y = [cos/sin(k*LN(x)) features] @ W + bias  == GEMM M=4096,N=512,K=32768 (bf16 MFMA)
// R4: B-operand read DIRECT from global (K-major, L2-resident stream) — no B LDS.
//     A double-buffered in LDS, ONE barrier per K-iter.
// ws layout: [0,16MB)  csT float2[512][4096] = (cos xn, sin xn) transposed seeds
//            [16MB]    mu_rs float2[4096] (32 KB)
//            [17MB]    bf16 weights [2][512][16384] (33.5 MB)
//            [51MB]    bf16 split-K partials [8][4096][512] (33.5 MB)

#define N_ROWS 4096
#define D_IN   512
#define D_OUT  512
#define KT     16384   // per-trig K = D_IN*G
#define BM 128
#define BN 128
#define BK 64
#define LDA 72         // padded LDS leading dim (bf16 units); 144B rows keep 16B align

typedef short short8 __attribute__((ext_vector_type(8)));
typedef float float4v __attribute__((ext_vector_type(4)));

__device__ inline unsigned int pack2bf(float a, float b) {
    __hip_bfloat162 h = __float22bfloat162_rn(make_float2(a, b));
    union { __hip_bfloat162 h; unsigned int u; } cv;
    cv.h = h;
    return cv.u;
}

__device__ inline unsigned short bf16_1(float a) {
    union { float f; unsigned int u; } cv;
    cv.f = a;
    unsigned int r = (cv.u + 0x7fff + ((cv.u >> 16) & 1)) >> 16;  // RN-even
    return (unsigned short)r;
}

// ---- kernel 1: per-row LayerNorm stats (mu, rsqrt(var+eps)) ----
__global__ __launch_bounds__(256) void ln_stats(const float* __restrict__ x,
        float2* __restrict__ mu_rs) {
    const int t = threadIdx.x;
    const int row = blockIdx.x * 4 + (t >> 6);
    const int lane = t & 63;
    const float4* xr = (const float4*)(x + (size_t)row * D_IN);
    float4 a = xr[lane];
    float4 c = xr[lane + 64];
    float s = a.x + a.y + a.z + a.w + c.x + c.y + c.z + c.w;
    float q = a.x * a.x + a.y * a.y + a.z * a.z + a.w * a.w
            + c.x * c.x + c.y * c.y + c.z * c.z + c.w * c.w;
    #pragma unroll
    for (int off = 32; off > 0; off >>= 1) {
        s += __shfl_down(s, off, 64);
        q += __shfl_down(q, off, 64);
    }
    if (lane == 0) {
        float mu = s * (1.f / D_IN);
        float var = q * (1.f / D_IN) - mu * mu;
        mu_rs[row] = make_float2(mu, rsqrtf(var + 1e-5f));
    }
}

// ---- kernel 2: normalize + sincos seeds, transposed coalesced write ----
__global__ __launch_bounds__(256) void feat_seed(const float* __restrict__ x,
        const float* __restrict__ w, const float* __restrict__ b,
        const float2* __restrict__ mu_rs, float2* __restrict__ csT) {
    __shared__ float2 tile[64][66];
    const int t = threadIdx.x;
    const int r0 = blockIdx.x * 64, i0 = blockIdx.y * 64;
    const int rr = t >> 6;      // 0..3
    const int cc = t & 63;
    const float wv = w[i0 + cc], bv = b[i0 + cc];
    #pragma unroll
    for (int p = 0; p < 16; ++p) {
        const int row = r0 + p * 4 + rr;
        float v = x[(size_t)row * D_IN + i0 + cc];
        float2 mr = mu_rs[row];
        float xn = (v - mr.x) * mr.y * wv + bv;
        float sn, cn;
        __sincosf(xn, &sn, &cn);
        tile[cc][p * 4 + rr] = make_float2(cn, sn);
    }
    __syncthreads();
    #pragma unroll
    for (int p = 0; p < 16; ++p) {
        const int dim = p * 4 + rr;
        csT[(size_t)(i0 + dim) * N_ROWS + r0 + cc] = tile[dim][cc];
    }
}

// ---- kernel 3: cast fouriercoeffs fp32 -> bf16 (layout preserved: [t][o][i*32+g]) ----
__global__ __launch_bounds__(256) void cvt_kernel(const float* __restrict__ fc,
        unsigned short* __restrict__ Wb) {
    size_t e = ((size_t)blockIdx.x * 256 + threadIdx.x) * 8;
    const float4* in = (const float4*)(fc + e);
    float4 a = in[0];
    float4 c = in[1];
    uint4 o;
    o.x = pack2bf(a.x, a.y);
    o.y = pack2bf(a.z, a.w);
    o.z = pack2bf(c.x, c.y);
    o.w = pack2bf(c.z, c.w);
    *(uint4*)(Wb + e) = o;
}

// ---- kernel 4: fused feature-gen + bf16 MFMA GEMM, split-K=8 ----
// grid (32 row-tiles, 4 col-tiles, 8 k-chunks); chunk>>2 = trig (0 cos / 1 sin)
// A: Chebyshev features staged in double-buffered LDS (one barrier/iter).
// B: direct global->VGPR 16B fragment loads (K-major weights, L2-hit stream).
__global__ __launch_bounds__(256, 3) void fkan_gemm(const float2* __restrict__ csT,
        const unsigned short* __restrict__ Wb, unsigned short* __restrict__ pb) {
    __shared__ unsigned short As[2][BM * LDA];
    const int t = threadIdx.x;
    const int row0 = blockIdx.x * BM;
    const int col0 = blockIdx.y * BN;
    const int chunk = blockIdx.z;
    const int ttype = chunk >> 2;
    const int k0 = (chunk & 3) * 4096;   // within-trig k offset
    const int i0 = k0 >> 5;              // starting input dim for this chunk
    // feature staging: thread -> (row, which-of-2-input-dims)
    const int frow = t & 127;
    const int ihalf = t >> 7;
    // wave/lane ids for MFMA
    const int l = t & 63, wv = t >> 6;
    const int wm = (wv & 1) * 64, wn = (wv >> 1) * 64;
    const int lm = l & 15, lq = l >> 4;

    // per-lane global B fragment pointers: col = col0+wn+tn*16+lm, k = k0+iter*64+h*32+lq*8
    const unsigned short* Bp[4];
    #pragma unroll
    for (int tn = 0; tn < 4; ++tn)
        Bp[tn] = Wb + (size_t)ttype * D_OUT * KT
               + (size_t)(col0 + wn + tn * 16 + lm) * KT + k0 + lq * 8;

    float4v acc[4][4];
    #pragma unroll
    for (int i = 0; i < 4; ++i)
        #pragma unroll
        for (int j = 0; j < 4; ++j)
            acc[i][j] = (float4v){0.f, 0.f, 0.f, 0.f};

    // prologue: seeds for iter 0, stage A(0) into As[0]
    float2 cs = csT[(size_t)(i0 + ihalf) * N_ROWS + row0 + frow];
    {
        const float c1 = cs.x, s1 = cs.y;
        const float c2 = 2.f * c1;
        float prev = ttype ? 0.f : 1.f;
        float cur  = ttype ? s1 : c1;
        uint4* dst = (uint4*)&As[0][frow * LDA + ihalf * 32];
        unsigned int us[4];
        #pragma unroll
        for (int d = 0; d < 16; ++d) {
            float f0 = cur;
            float f1 = c2 * cur - prev;
            float f2 = c2 * f1 - cur;
            prev = f1;
            cur = f2;
            us[d & 3] = pack2bf(f0, f1);
            if ((d & 3) == 3)
                dst[d >> 2] = make_uint4(us[0], us[1], us[2], us[3]);
        }
    }
    cs = csT[(size_t)(i0 + 2 + ihalf) * N_ROWS + row0 + frow];  // seeds for iter 1
    __syncthreads();

    for (int iter = 0; iter < 64; ++iter) {
        const int p = iter & 1;
        // ---- B fragments for this iter: direct global loads (latency hidden
        //      behind the feature-VALU chain below)
        short8 bfr[2][4];
        #pragma unroll
        for (int h = 0; h < 2; ++h)
            #pragma unroll
            for (int tn = 0; tn < 4; ++tn)
                bfr[h][tn] = *(const short8*)(Bp[tn] + iter * 64 + h * 32);
        // ---- stage A(iter+1) into the other LDS buffer
        if (iter < 63) {
            const float c1 = cs.x, s1 = cs.y;
            const float c2 = 2.f * c1;
            float prev = ttype ? 0.f : 1.f;
            float cur  = ttype ? s1 : c1;
            uint4* dst = (uint4*)&As[p ^ 1][frow * LDA + ihalf * 32];
            unsigned int us[4];
            #pragma unroll
            for (int d = 0; d < 16; ++d) {
                float f0 = cur;
                float f1 = c2 * cur - prev;
                float f2 = c2 * f1 - cur;
                prev = f1;
                cur = f2;
                us[d & 3] = pack2bf(f0, f1);
                if ((d & 3) == 3)
                    dst[d >> 2] = make_uint4(us[0], us[1], us[2], us[3]);
            }
            if (iter < 62)
                cs = csT[(size_t)(i0 + (iter + 2) * 2 + ihalf) * N_ROWS + row0 + frow];
        }
        // ---- MFMA on As[p] (published by previous iter's barrier)
        #pragma unroll
        for (int h = 0; h < 2; ++h) {
            short8 af[4];
            #pragma unroll
            for (int tm = 0; tm < 4; ++tm)
                af[tm] = *(const short8*)&As[p][(wm + tm * 16 + lm) * LDA + h * 32 + lq * 8];
            #pragma unroll
            for (int tm = 0; tm < 4; ++tm)
                #pragma unroll
                for (int tn = 0; tn < 4; ++tn)
                    acc[tm][tn] = __builtin_amdgcn_mfma_f32_16x16x32_bf16(
                        af[tm], bfr[h][tn], acc[tm][tn], 0, 0, 0);
        }
        __syncthreads();   // publish As[p^1], protect As[p] for next overwrite
    }
    // epilogue: C/D layout col=lane&15, row=quad*4+reg (m89-verified)
    unsigned short* pc = pb + (size_t)chunk * N_ROWS * D_OUT;
    #pragma unroll
    for (int tm = 0; tm < 4; ++tm)
        #pragma unroll
        for (int tn = 0; tn < 4; ++tn)
            #pragma unroll
            for (int r = 0; r < 4; ++r) {
                int row = row0 + wm + tm * 16 + lq * 4 + r;
                int col = col0 + wn + tn * 16 + lm;
                pc[(size_t)row * D_OUT + col] = bf16_1(acc[tm][tn][r]);
            }
}

// ---- kernel 5: out = bias + sum of 8 bf16 partials (coalesced) ----
__global__ __launch_bounds__(256) void reduce_kernel(const unsigned short* __restrict__ pb,
        const float* __restrict__ bias, float* __restrict__ out) {
    const size_t e = ((size_t)blockIdx.x * 256 + threadIdx.x) * 4;
    const int col = (int)(e & (D_OUT - 1));
    float4 s = *(const float4*)(bias + col);
    #pragma unroll
    for (int c = 0; c < 8; ++c) {
        ushort4 u = *(const ushort4*)(pb + (size_t)c * N_ROWS * D_OUT + e);
        union { unsigned int u; float f; } f0, f1, f2, f3;
        f0.u = (unsigned int)u.x << 16;
        f1.u = (unsigned int)u.y << 16;
        f2.u = (unsigned int)u.z << 16;
        f3.u = (unsigned int)u.w << 16;
        s.x += f0.f; s.y += f1.f; s.z += f2.f; s.w += f3.f;
    }
    *(float4*)(out + e) = s;
}

extern "C" void kernel_launch(void* const* d_in, const int* in_sizes, int n_in,
                              void* d_out, int out_size, void* d_ws, size_t ws_size,
                              hipStream_t stream) {
    const float* x    = (const float*)d_in[0];
    const float* ln_w = (const float*)d_in[1];
    const float* ln_b = (const float*)d_in[2];
    const float* fc   = (const float*)d_in[3];
    const float* bias = (const float*)d_in[4];
    float* out = (float*)d_out;

    float2* csT = (float2*)d_ws;                                        // 16 MB
    float2* mu_rs = (float2*)((char*)d_ws + (16u << 20));               // 32 KB
    unsigned short* Wb = (unsigned short*)((char*)d_ws + (17u << 20));  // 33.5 MB
    unsigned short* pbp = (unsigned short*)((char*)d_ws + (51u << 20)); // 33.5 MB

    ln_stats<<<N_ROWS / 4, 256, 0, stream>>>(x, mu_rs);
    feat_seed<<<dim3(N_ROWS / 64, D_IN / 64), 256, 0, stream>>>(x, ln_w, ln_b, mu_rs, csT);
    cvt_kernel<<<8192, 256, 0, stream>>>(fc, Wb);                       // 16.78M elems
    fkan_gemm<<<dim3(N_ROWS / BM, D_OUT / BN, 8), 256, 0, stream>>>(csT, Wb, pbp);
    reduce_kernel<<<2048, 256, 0, stream>>>(pbp, bias, out);            // 2.10M outs
}